// Round 17
// baseline (113.856 us; speedup 1.0000x reference)
//
#include <hip/hip_runtime.h>
#include <math.h>

typedef float f4 __attribute__((ext_vector_type(4)));
typedef float f32x4 __attribute__((ext_vector_type(4)));
typedef __bf16 bf16x8 __attribute__((ext_vector_type(8)));
typedef unsigned short u16;
typedef u16 us8 __attribute__((ext_vector_type(8)));

__device__ __forceinline__ u16 f2bf(float f) {
  unsigned u = __builtin_bit_cast(unsigned, f);
  unsigned r = u + 0x7fffu + ((u >> 16) & 1u);
  return (u16)(r >> 16);
}
__device__ __forceinline__ float bf2f(u16 h) {
  unsigned u = ((unsigned)h) << 16;
  return __builtin_bit_cast(float, u);
}

// scale[d] = rsqrt(var+eps)*gamma ; shift[d] = beta - mean*scale
__global__ __launch_bounds__(256) void prep_bn_kernel(
    const float* __restrict__ gamma, const float* __restrict__ beta,
    const float* __restrict__ mean, const float* __restrict__ var,
    float* __restrict__ scale, float* __restrict__ shift) {
  int d = blockIdx.x * blockDim.x + threadIdx.x;
  if (d < 512) {
    float s = rsqrtf(var[d] + 1e-3f) * gamma[d];
    scale[d] = s;
    shift[d] = beta[d] - mean[d] * s;
  }
}

// Pth[j][k] (bf16, [512][1024]): k<512 -> coefs^2 ; k>=512 -> -2*coefs^2*centers
// cvec[j] = sum_d coefs^2*centers^2  (fp32)
__global__ __launch_bounds__(64) void prep_params_kernel(
    const float* __restrict__ coefs, const float* __restrict__ centers,
    u16* __restrict__ pth, float* __restrict__ cvec) {
  int j = blockIdx.x;
  int l = threadIdx.x;
  int d0 = l * 8;
  f4 c0 = *(const f4*)(coefs + (size_t)j * 512 + d0);
  f4 c1 = *(const f4*)(coefs + (size_t)j * 512 + d0 + 4);
  f4 e0 = *(const f4*)(centers + (size_t)j * 512 + d0);
  f4 e1 = *(const f4*)(centers + (size_t)j * 512 + d0 + 4);
  us8 pa, pb;
  float acc = 0.f;
#pragma unroll
  for (int e = 0; e < 8; ++e) {
    float cf = (e < 4) ? c0[e] : c1[e - 4];
    float ce = (e < 4) ? e0[e] : e1[e - 4];
    float a = cf * cf;
    pa[e] = f2bf(a);
    pb[e] = f2bf(-2.f * a * ce);
    acc = fmaf(a * ce, ce, acc);
  }
  *(us8*)(pth + (size_t)j * 1024 + d0) = pa;
  *(us8*)(pth + (size_t)j * 1024 + 512 + d0) = pb;
#pragma unroll
  for (int off = 32; off; off >>= 1) acc += __shfl_xor(acc, off);
  if (l == 0) cvec[j] = acc;
}

// Transpose [K][N] fp32 -> Th [N][K] bf16; optional per-k rescale (1/scale_k)
__global__ __launch_bounds__(256) void transpose_split_kernel(
    const float* __restrict__ in, u16* __restrict__ th,
    const float* __restrict__ scale, int K, int N) {
  __shared__ float t[32][33];
  int lx = threadIdx.x;  // 32
  int ly = threadIdx.y;  // 8
  int n0 = blockIdx.x * 32, k0 = blockIdx.y * 32;
#pragma unroll
  for (int i = 0; i < 4; ++i)
    t[ly + 8 * i][lx] = in[(size_t)(k0 + ly + 8 * i) * N + n0 + lx];
  __syncthreads();
  float rs = scale ? (1.0f / scale[k0 + lx]) : 1.0f;
#pragma unroll
  for (int i = 0; i < 4; ++i) {
    float v = t[lx][ly + 8 * i] * rs;
    th[(size_t)(n0 + ly + 8 * i) * K + k0 + lx] = f2bf(v);
  }
}

// b1a[j] = b1[j] - sum_k shift_k * W1[k][j] / scale_k   (8 blocks x 256 thr)
__global__ __launch_bounds__(256) void b1adj_kernel(
    const float* __restrict__ W1, const float* __restrict__ b1,
    const float* __restrict__ scale, const float* __restrict__ shift,
    float* __restrict__ b1a) {
  __shared__ float red[4][64];
  int b = blockIdx.x;
  int lane = threadIdx.x & 63;
  int kq = threadIdx.x >> 6;
  int j = b * 64 + lane;
  float partial = 0.f;
  for (int i = 0; i < 128; ++i) {
    int k = kq * 128 + i;
    partial = fmaf(shift[k] / scale[k], W1[(size_t)k * 512 + j], partial);
  }
  red[kq][lane] = partial;
  __syncthreads();
  if (threadIdx.x < 64) {
    float t = red[0][threadIdx.x] + red[1][threadIdx.x] +
              red[2][threadIdx.x] + red[3][threadIdx.x];
    b1a[b * 64 + threadIdx.x] = b1[b * 64 + threadIdx.x] - t;
  }
}

// x [16384][512] fp32 -> Xb = bf16(xb), Xsq = bf16(xb*xb); xb = x*scale+shift
__global__ __launch_bounds__(256) void conv_x_kernel(
    const float* __restrict__ x, const float* __restrict__ scale,
    const float* __restrict__ shift, u16* __restrict__ xb,
    u16* __restrict__ xsq) {
  int gid = blockIdx.x * 256 + threadIdx.x;
  int m = gid >> 6;
  int d0 = (gid & 63) * 8;
  f4 v0 = *(const f4*)(x + (size_t)m * 512 + d0);
  f4 v1 = *(const f4*)(x + (size_t)m * 512 + d0 + 4);
  f4 s0 = *(const f4*)(scale + d0);
  f4 s1 = *(const f4*)(scale + d0 + 4);
  f4 h0 = *(const f4*)(shift + d0);
  f4 h1 = *(const f4*)(shift + d0 + 4);
  us8 ob, oq;
#pragma unroll
  for (int e = 0; e < 8; ++e) {
    float xv = (e < 4) ? v0[e] : v1[e - 4];
    float sc = (e < 4) ? s0[e] : s1[e - 4];
    float sh = (e < 4) ? h0[e] : h1[e - 4];
    float xbf = fmaf(xv, sc, sh);
    ob[e] = f2bf(xbf);
    oq[e] = f2bf(xbf * xbf);
  }
  *(us8*)(xb + (size_t)m * 512 + d0) = ob;
  *(us8*)(xsq + (size_t)m * 512 + d0) = oq;
}

__device__ __forceinline__ void wait_vm8() {
  asm volatile("s_waitcnt vmcnt(8)" ::: "memory");
}
__device__ __forceinline__ void wait_vm0() {
  asm volatile("s_waitcnt vmcnt(0)" ::: "memory");
}
__device__ __forceinline__ void sbar() { __builtin_amdgcn_s_barrier(); }
__device__ __forceinline__ void sgb0() { __builtin_amdgcn_sched_barrier(0); }

// Merged G1+G2, counted-vmcnt 2-tile-ahead pipeline. 1024 blocks, 128x128,
// BK=64, LDS 64KB. g==0: A = Xb (rescaled-W1 trick), K=512, bias=b1a.
// g==1: A = (k<512 ? Xsq : Xb), K=1024 vs Pth, bias=cvec.
__global__ __launch_bounds__(256, 2) void gemm_fused12(
    const u16* __restrict__ Xb, const u16* __restrict__ Xsq,
    const u16* __restrict__ W1th, const u16* __restrict__ Pth,
    const float* __restrict__ b1a, const float* __restrict__ cvec,
    u16* __restrict__ Hout) {
  extern __shared__ char smem[];
  const int tid = threadIdx.x;
  const int l = tid & 63;
  const int w = tid >> 6;
  const int wm = w & 1, wn = w >> 1;
  const int lr = l & 15, lk = l >> 4;
  const int sx = lr & 7;
  const int bid = blockIdx.x;
  const int L = (bid & 7) * 128 + (bid >> 3);
  const int p = L >> 3;
  const int g = ((L >> 2) & 1) ^ 1;
  const int n = L & 3;
  const int m0 = p * 128, n0 = n * 128;
  const int Kg = g ? 1024 : 512;
  const int nt = g ? 16 : 8;
  const u16* Bmat = g ? Pth : W1th;
  const int srow = l >> 3;
  const int sslot = (l & 7) ^ srow;

  f32x4 acc[4][4];
#pragma unroll
  for (int i = 0; i < 4; ++i)
#pragma unroll
    for (int j = 0; j < 4; ++j) acc[i][j] = (f32x4){0.f, 0.f, 0.f, 0.f};

#define F12_STAGE(buf, k0)                                                    \
  {                                                                           \
    const u16* Asrc = g ? (((k0) < 512) ? Xsq : Xb) : Xb;                     \
    const int kb = (k0)&511;                                                  \
    char* dA = smem + (buf)*16384;                                            \
    char* dB = smem + 32768 + (buf)*16384;                                    \
    _Pragma("unroll") for (int pp = 0; pp < 4; ++pp) {                        \
      int c = pp * 4 + w;                                                     \
      int row = c * 8 + srow;                                                 \
      int loff = c * 1024;                                                    \
      size_t goa = (size_t)(m0 + row) * 512 + kb + sslot * 8;                 \
      size_t gob = (size_t)(n0 + row) * Kg + (k0) + sslot * 8;                \
      __builtin_amdgcn_global_load_lds(                                       \
          (const __attribute__((address_space(1))) void*)(Asrc + goa),        \
          (__attribute__((address_space(3))) void*)(dA + loff), 16, 0, 0);    \
      __builtin_amdgcn_global_load_lds(                                       \
          (const __attribute__((address_space(1))) void*)(Bmat + gob),        \
          (__attribute__((address_space(3))) void*)(dB + loff), 16, 0, 0);    \
    }                                                                         \
  }

  F12_STAGE(0, 0);
  F12_STAGE(1, 64);
  for (int t = 0; t < nt; ++t) {
    if (t + 1 < nt) {
      wait_vm8();
    } else {
      wait_vm0();
    }
    sgb0();
    sbar();
    sgb0();
    const char* sA = smem + (t & 1) * 16384;
    const char* sB = smem + 32768 + (t & 1) * 16384;
#pragma unroll
    for (int ks = 0; ks < 2; ++ks) {
      bf16x8 av[4], bv[4];
#pragma unroll
      for (int i = 0; i < 4; ++i)
        av[i] = *(const bf16x8*)(sA + (wm * 64 + i * 16 + lr) * 128 +
                                 (((ks * 4 + lk) ^ sx) * 16));
#pragma unroll
      for (int j = 0; j < 4; ++j)
        bv[j] = *(const bf16x8*)(sB + (wn * 64 + j * 16 + lr) * 128 +
                                 (((ks * 4 + lk) ^ sx) * 16));
#pragma unroll
      for (int i = 0; i < 4; ++i)
#pragma unroll
        for (int j = 0; j < 4; ++j)
          acc[i][j] = __builtin_amdgcn_mfma_f32_16x16x32_bf16(av[i], bv[j],
                                                              acc[i][j], 0, 0, 0);
    }
    sgb0();
    sbar();
    sgb0();
    if (t + 2 < nt) F12_STAGE(t & 1, (t + 2) * 64);
  }
#undef F12_STAGE

  const int mwb = m0 + wm * 64;
  const int nwb = n0 + wn * 64;
  const float* bias = g ? cvec : b1a;
#pragma unroll
  for (int j = 0; j < 4; ++j) {
    int nn = nwb + j * 16 + lr;
    float bv = bias[nn];
#pragma unroll
    for (int i = 0; i < 4; ++i) {
#pragma unroll
      for (int r = 0; r < 4; ++r) {
        int m = mwb + i * 16 + lk * 4 + r;
        float v = acc[i][j][r] + bv;
        v = g ? fmaxf(1.f - v, 0.f) : fmaxf(v, 0.f);
        Hout[(size_t)m * 1024 + g * 512 + nn] = f2bf(v);
      }
    }
  }
}

// G3: pre = w0*x + w1*relu(Hh @ Wth^T + b_out), stored BF16.
// K=1024, counted-vmcnt 2-ahead pipeline, LDS 64KB. 512 blocks, XCD swizzle.
__global__ __launch_bounds__(256, 2) void gemm3(
    const u16* __restrict__ Ah, const u16* __restrict__ Bh,
    const float* __restrict__ bias, const float* __restrict__ xorig,
    const float* __restrict__ wadd, u16* __restrict__ preb) {
  extern __shared__ char smem[];
  const int tid = threadIdx.x;
  const int l = tid & 63;
  const int w = tid >> 6;
  const int wm = w & 1, wn = w >> 1;
  const int lr = l & 15, lk = l >> 4;
  const int sx = lr & 7;
  const int bid = blockIdx.x;
  const int lin = (bid & 7) * 64 + (bid >> 3);
  const int m0 = (lin >> 2) * 128, n0 = (lin & 3) * 128;
  const int srow = l >> 3;
  const int sslot = (l & 7) ^ srow;

  f32x4 acc[4][4];
#pragma unroll
  for (int i = 0; i < 4; ++i)
#pragma unroll
    for (int j = 0; j < 4; ++j) acc[i][j] = (f32x4){0.f, 0.f, 0.f, 0.f};

#define G3_STAGE(buf, k0)                                                     \
  {                                                                           \
    char* dA = smem + (buf)*16384;                                            \
    char* dB = smem + 32768 + (buf)*16384;                                    \
    _Pragma("unroll") for (int pp = 0; pp < 4; ++pp) {                        \
      int c = pp * 4 + w;                                                     \
      int row = c * 8 + srow;                                                 \
      int loff = c * 1024;                                                    \
      size_t gob = (size_t)(n0 + row) * 1024 + (k0) + sslot * 8;              \
      size_t goa = (size_t)(m0 + row) * 1024 + (k0) + sslot * 8;              \
      __builtin_amdgcn_global_load_lds(                                       \
          (const __attribute__((address_space(1))) void*)(Bh + gob),          \
          (__attribute__((address_space(3))) void*)(dB + loff), 16, 0, 0);    \
      __builtin_amdgcn_global_load_lds(                                       \
          (const __attribute__((address_space(1))) void*)(Ah + goa),          \
          (__attribute__((address_space(3))) void*)(dA + loff), 16, 0, 0);    \
    }                                                                         \
  }

  G3_STAGE(0, 0);
  G3_STAGE(1, 64);
  for (int t = 0; t < 16; ++t) {
    if (t + 1 < 16) {
      wait_vm8();
    } else {
      wait_vm0();
    }
    sgb0();
    sbar();
    sgb0();
    const char* sA = smem + (t & 1) * 16384;
    const char* sB = smem + 32768 + (t & 1) * 16384;
#pragma unroll
    for (int ks = 0; ks < 2; ++ks) {
      bf16x8 av[4], bv[4];
#pragma unroll
      for (int i = 0; i < 4; ++i)
        av[i] = *(const bf16x8*)(sA + (wm * 64 + i * 16 + lr) * 128 +
                                 (((ks * 4 + lk) ^ sx) * 16));
#pragma unroll
      for (int j = 0; j < 4; ++j)
        bv[j] = *(const bf16x8*)(sB + (wn * 64 + j * 16 + lr) * 128 +
                                 (((ks * 4 + lk) ^ sx) * 16));
#pragma unroll
      for (int i = 0; i < 4; ++i)
#pragma unroll
        for (int j = 0; j < 4; ++j)
          acc[i][j] = __builtin_amdgcn_mfma_f32_16x16x32_bf16(av[i], bv[j],
                                                              acc[i][j], 0, 0, 0);
    }
    sgb0();
    sbar();
    sgb0();
    if (t + 2 < 16) G3_STAGE(t & 1, (t + 2) * 64);
  }
#undef G3_STAGE

  const int mwb = m0 + wm * 64;
  const int nwb = n0 + wn * 64;
  float w0 = wadd[0], w1 = wadd[1];
#pragma unroll
  for (int j = 0; j < 4; ++j) {
    int n = nwb + j * 16 + lr;
    float bv = bias[n];
#pragma unroll
    for (int i = 0; i < 4; ++i) {
#pragma unroll
      for (int r = 0; r < 4; ++r) {
        int m = mwb + i * 16 + lk * 4 + r;
        float v = fmaxf(acc[i][j][r] + bv, 0.f);
        preb[(size_t)m * 512 + n] =
            f2bf(fmaf(w1, v, w0 * xorig[(size_t)m * 512 + n]));
      }
    }
  }
}

// One wave per row of 512: read bf16 pre, sparsemax in f32, write f32 mask.
__global__ __launch_bounds__(256) void sparsemax_kernel(
    const u16* __restrict__ pre, float* __restrict__ out) {
  int wrk = (blockIdx.x & 7) * 512 + (blockIdx.x >> 3);
  int row = wrk * 4 + (threadIdx.x >> 6);
  int lane = threadIdx.x & 63;
  const u16* rp = pre + (size_t)row * 512;
  us8 zv = *(const us8*)(rp + lane * 8);
  float z[8];
#pragma unroll
  for (int e = 0; e < 8; ++e) z[e] = bf2f(zv[e]);
  float m = z[0];
#pragma unroll
  for (int i = 1; i < 8; ++i) m = fmaxf(m, z[i]);
#pragma unroll
  for (int off = 32; off; off >>= 1) m = fmaxf(m, __shfl_xor(m, off));
  float tau = m - 1.0f;
  for (int it = 0; it < 32; ++it) {
    float s = 0.f, k = 0.f;
#pragma unroll
    for (int i = 0; i < 8; ++i) {
      if (z[i] > tau) {
        s += z[i] - tau;
        k += 1.f;
      }
    }
#pragma unroll
    for (int off = 32; off; off >>= 1) {
      s += __shfl_xor(s, off);
      k += __shfl_xor(k, off);
    }
    if (k < 0.5f) break;
    float tn = tau + (s - 1.f) / k;
    if (tn == tau) break;
    tau = tn;
  }
  float s = 0.f, k = 0.f;
#pragma unroll
  for (int i = 0; i < 8; ++i)
    if (z[i] > tau) {
      s += z[i];
      k += 1.f;
    }
#pragma unroll
  for (int off = 32; off; off >>= 1) {
    s += __shfl_xor(s, off);
    k += __shfl_xor(k, off);
  }
  float tauf = (k >= 0.5f) ? (s - 1.f) / k : (m - 1.f);
  float* op = out + (size_t)row * 512 + lane * 8;
  f4 o0, o1;
#pragma unroll
  for (int e = 0; e < 4; ++e) {
    o0[e] = fmaxf(z[e] - tauf, 0.f);
    o1[e] = fmaxf(z[4 + e] - tauf, 0.f);
  }
  *(f4*)(op) = o0;
  *(f4*)(op + 4) = o1;
}

extern "C" void kernel_launch(void* const* d_in, const int* in_sizes, int n_in,
                              void* d_out, int out_size, void* d_ws,
                              size_t ws_size, hipStream_t stream) {
  const float* x = (const float*)d_in[0];
  const float* W1 = (const float*)d_in[1];
  const float* b1 = (const float*)d_in[2];
  const float* centers = (const float*)d_in[3];
  const float* coefs = (const float*)d_in[4];
  const float* gamma = (const float*)d_in[5];
  const float* beta = (const float*)d_in[6];
  const float* mean = (const float*)d_in[7];
  const float* var = (const float*)d_in[8];
  const float* W_out = (const float*)d_in[9];
  const float* b_out = (const float*)d_in[10];
  const float* wadd = (const float*)d_in[11];
  float* out = (float*)d_out;

  // Layout within the round-1-proven 69,212,160 B floor:
  char* ws = (char*)d_ws;
  u16* Hh = (u16*)(ws);                      // [16384][1024] bf16 = 32 MB
  float* b1a = (float*)(ws + 33554432);      // 2 KB   (freed Xh slot)
  u16* Wth = (u16*)(ws + 33562624);          // [512][1024] bf16 = 1 MB
  u16* Xb = (u16*)(ws + 50331648);           // [16384][512] bf16 = 16 MB
  u16* Pth = (u16*)(ws + 67108864);          // [512][1024] bf16 = 1 MB
  u16* W1th = (u16*)(ws + 68157440);         // [512][512] bf16 = 0.5 MB
  float* cvec = (float*)(ws + 69206016);     // 2 KB
  float* scale = (float*)(ws + 69208064);    // 2 KB
  float* shift = (float*)(ws + 69210112);    // 2 KB
  // Xsq in d_out (32 MB fp32): dead scratch until sparsemax overwrites it.
  u16* Xsq = (u16*)d_out;
  // bf16 pre reuses the Xb slot (dead after fused12, stream-ordered).
  u16* preb = Xb;

  prep_bn_kernel<<<2, 256, 0, stream>>>(gamma, beta, mean, var, scale, shift);
  prep_params_kernel<<<512, 64, 0, stream>>>(coefs, centers, Pth, cvec);
  // W1 transpose with 1/scale_k rescale (after prep_bn, stream-ordered).
  transpose_split_kernel<<<dim3(16, 16), dim3(32, 8), 0, stream>>>(
      W1, W1th, scale, 512, 512);
  b1adj_kernel<<<8, 256, 0, stream>>>(W1, b1, scale, shift, b1a);
  transpose_split_kernel<<<dim3(16, 32), dim3(32, 8), 0, stream>>>(
      W_out, Wth, nullptr, 1024, 512);
  conv_x_kernel<<<4096, 256, 0, stream>>>(x, scale, shift, Xb, Xsq);

  gemm_fused12<<<1024, 256, 65536, stream>>>(Xb, Xsq, W1th, Pth, b1a, cvec,
                                             Hh);
  gemm3<<<512, 256, 65536, stream>>>(Hh, Wth, b_out, x, wadd, preb);
  sparsemax_kernel<<<4096, 256, 0, stream>>>(preb, out);
}